// Round 1
// baseline (779.907 us; speedup 1.0000x reference)
//
#include <hip/hip_runtime.h>
#include <hip/hip_bf16.h>

// Problem constants
#define BATCH 4096
#define FEATS 26
#define BAG   8
#define EDIM  64
#define INDIM 1664   // 26*64

typedef short bf16x8 __attribute__((ext_vector_type(8)));
typedef float f32x4  __attribute__((ext_vector_type(4)));

__device__ __forceinline__ unsigned short f2bf(float f) {
    unsigned u = __float_as_uint(f);
    unsigned r = (u + 0x7FFFu + ((u >> 16) & 1u)) >> 16;
    return (unsigned short)r;
}

// ---------------- embedding bag: gather + sum-pool ----------------
// one wave per (b, f) bag; lane = d in [0,64)
__global__ __launch_bounds__(256) void embed_pool(
    const int* __restrict__ x, const float* __restrict__ emb,
    float* __restrict__ feat)
{
    int bag  = blockIdx.x * 4 + (threadIdx.x >> 6);   // [0, BATCH*FEATS)
    int lane = threadIdx.x & 63;
    int b = bag / FEATS;
    int f = bag - b * FEATS;
    const int* xs = x + (long long)bag * BAG;
    float s = 0.f;
#pragma unroll
    for (int l = 0; l < BAG; ++l) {
        int id = xs[l];
        s += emb[(long long)id * EDIM + lane];
    }
    feat[(long long)b * INDIM + f * EDIM + lane] = s;
}

// ---------------- bf16 MFMA GEMM, 128x128 tile, BK=32 ----------------
// C = relu?(A @ W + bias [+ res]) ; A [M,K] fp32, W [K,N] fp32, out fp32
#define LDT 40   // padded LDS row (shorts): 80 B = 20-bank stride, 16B-aligned reads
__global__ __launch_bounds__(256) void gemm_bf16(
    const float* __restrict__ A, const float* __restrict__ W,
    const float* __restrict__ bias, const float* __restrict__ res,
    float* __restrict__ out, int M, int N, int K, int do_relu)
{
    __shared__ unsigned short As[128][LDT];
    __shared__ unsigned short Bs[128][LDT];

    const int t    = threadIdx.x;
    const int bCol = blockIdx.x * 128;
    const int bRow = blockIdx.y * 128;
    const int wave = t >> 6, lane = t & 63;
    const int wm = wave & 1, wn = wave >> 1;
    const int lm = lane & 15, quad = lane >> 4;

    f32x4 acc[4][4] = {};

    // A staging map: row = t/8 (+i*32), k = (t%8)*4  (float4 loads, 8B LDS writes)
    const int arow = t >> 3;
    const int ak   = (t & 7) * 4;
    // B staging map: n = t&127, kbase = (t>>7)*4 (+i*8)  (coalesced dword loads,
    // k-contiguous 8B LDS writes -> no transpose bank storm)
    const int bn  = t & 127;
    const int bk0 = (t >> 7) * 4;

    for (int kt = 0; kt < K; kt += 32) {
        // ---- stage A (fp32 -> bf16) ----
#pragma unroll
        for (int i = 0; i < 4; ++i) {
            int row = arow + i * 32;
            float4 v = *(const float4*)(A + (long long)(bRow + row) * K + kt + ak);
            unsigned short* dst = &As[row][ak];
            dst[0] = f2bf(v.x); dst[1] = f2bf(v.y);
            dst[2] = f2bf(v.z); dst[3] = f2bf(v.w);
        }
        // ---- stage B (fp32 -> bf16, stored [n][k]) ----
#pragma unroll
        for (int i = 0; i < 4; ++i) {
            int kb = bk0 + i * 8;
            float v0 = W[(long long)(kt + kb + 0) * N + bCol + bn];
            float v1 = W[(long long)(kt + kb + 1) * N + bCol + bn];
            float v2 = W[(long long)(kt + kb + 2) * N + bCol + bn];
            float v3 = W[(long long)(kt + kb + 3) * N + bCol + bn];
            unsigned short* dst = &Bs[bn][kb];
            dst[0] = f2bf(v0); dst[1] = f2bf(v1);
            dst[2] = f2bf(v2); dst[3] = f2bf(v3);
        }
        __syncthreads();

        bf16x8 a[4], b[4];
#pragma unroll
        for (int i = 0; i < 4; ++i)
            a[i] = *(const bf16x8*)&As[wm * 64 + i * 16 + lm][quad * 8];
#pragma unroll
        for (int j = 0; j < 4; ++j)
            b[j] = *(const bf16x8*)&Bs[wn * 64 + j * 16 + lm][quad * 8];
#pragma unroll
        for (int i = 0; i < 4; ++i)
#pragma unroll
            for (int j = 0; j < 4; ++j)
                acc[i][j] = __builtin_amdgcn_mfma_f32_16x16x32_bf16(
                    a[i], b[j], acc[i][j], 0, 0, 0);
        __syncthreads();
    }

    // ---- epilogue: bias (+res) (+relu), fp32 out ----
#pragma unroll
    for (int i = 0; i < 4; ++i) {
#pragma unroll
        for (int j = 0; j < 4; ++j) {
            int col = bCol + wn * 64 + j * 16 + lm;
            float bv = bias[col];
#pragma unroll
            for (int r = 0; r < 4; ++r) {
                int row = bRow + wm * 64 + i * 16 + quad * 4 + r;
                float v = acc[i][j][r] + bv;
                if (res) v += res[(long long)row * N + col];
                if (do_relu) v = fmaxf(v, 0.f);
                out[(long long)row * N + col] = v;
            }
        }
    }
}

// ---------------- final linear + sigmoid ----------------
// one wave per batch row
__global__ __launch_bounds__(256) void final_head(
    const float* __restrict__ feat, const float* __restrict__ lin_w,
    const float* __restrict__ lin_b, float* __restrict__ out)
{
    int row  = blockIdx.x * 4 + (threadIdx.x >> 6);
    int lane = threadIdx.x & 63;
    const float* fr = feat + (long long)row * INDIM;
    float s = 0.f;
#pragma unroll
    for (int it = 0; it < INDIM / 64; ++it)
        s += fr[it * 64 + lane] * lin_w[it * 64 + lane];
#pragma unroll
    for (int off = 32; off; off >>= 1)
        s += __shfl_down(s, off, 64);
    if (lane == 0)
        out[row] = 1.f / (1.f + __expf(-(s + lin_b[0])));
}

extern "C" void kernel_launch(void* const* d_in, const int* in_sizes, int n_in,
                              void* d_out, int out_size, void* d_ws, size_t ws_size,
                              hipStream_t stream) {
    const int*   x    = (const int*)  d_in[0];
    const float* emb  = (const float*)d_in[1];
    const float* w1_0 = (const float*)d_in[2];
    const float* b1_0 = (const float*)d_in[3];
    const float* w2_0 = (const float*)d_in[4];
    const float* b2_0 = (const float*)d_in[5];
    const float* w1_1 = (const float*)d_in[6];
    const float* b1_1 = (const float*)d_in[7];
    const float* w2_1 = (const float*)d_in[8];
    const float* b2_1 = (const float*)d_in[9];
    const float* w1_2 = (const float*)d_in[10];
    const float* b1_2 = (const float*)d_in[11];
    const float* w2_2 = (const float*)d_in[12];
    const float* b2_2 = (const float*)d_in[13];
    const float* linw = (const float*)d_in[14];
    const float* linb = (const float*)d_in[15];
    float* out = (float*)d_out;

    float* feat = (float*)d_ws;                         // [4096, 1664] fp32
    float* h    = feat + (long long)BATCH * INDIM;      // [4096, 1024] fp32

    // 1) embedding bag
    embed_pool<<<BATCH * FEATS / 4, 256, 0, stream>>>(x, emb, feat);

    // 2) residual blocks
    // block 0: h = relu(feat@w1_0 + b1_0); feat = relu(h@w2_0 + b2_0 + feat)
    gemm_bf16<<<dim3(1024 / 128, BATCH / 128), 256, 0, stream>>>(
        feat, w1_0, b1_0, nullptr, h, BATCH, 1024, INDIM, 1);
    gemm_bf16<<<dim3(INDIM / 128, BATCH / 128), 256, 0, stream>>>(
        h, w2_0, b2_0, feat, feat, BATCH, INDIM, 1024, 1);
    // block 1
    gemm_bf16<<<dim3(1024 / 128, BATCH / 128), 256, 0, stream>>>(
        feat, w1_1, b1_1, nullptr, h, BATCH, 1024, INDIM, 1);
    gemm_bf16<<<dim3(INDIM / 128, BATCH / 128), 256, 0, stream>>>(
        h, w2_1, b2_1, feat, feat, BATCH, INDIM, 1024, 1);
    // block 2 (hidden 512)
    gemm_bf16<<<dim3(512 / 128, BATCH / 128), 256, 0, stream>>>(
        feat, w1_2, b1_2, nullptr, h, BATCH, 512, INDIM, 1);
    gemm_bf16<<<dim3(INDIM / 128, BATCH / 128), 256, 0, stream>>>(
        h, w2_2, b2_2, feat, feat, BATCH, INDIM, 512, 1);

    // 3) head
    final_head<<<BATCH / 4, 256, 0, stream>>>(feat, linw, linb, out);
}

// Round 2
// 646.968 us; speedup vs baseline: 1.2055x; 1.2055x over previous
//
#include <hip/hip_runtime.h>
#include <hip/hip_bf16.h>

// Problem constants
#define BATCH 4096
#define FEATS 26
#define BAG   8
#define EDIM  64
#define INDIM 1664   // 26*64

typedef short bf16x8 __attribute__((ext_vector_type(8)));
typedef float f32x4  __attribute__((ext_vector_type(4)));
typedef unsigned short u16x8 __attribute__((ext_vector_type(8)));

__device__ __forceinline__ unsigned short f2bf(float f) {
    unsigned u = __float_as_uint(f);
    unsigned r = (u + 0x7FFFu + ((u >> 16) & 1u)) >> 16;
    return (unsigned short)r;
}
__device__ __forceinline__ float bf2f(unsigned short h) {
    return __uint_as_float((unsigned)h << 16);
}
// async global->LDS, 16B per lane. HW dst = wave-uniform base + lane*16.
__device__ __forceinline__ void async_cp16(const void* g, void* lds_base_uniform) {
    __builtin_amdgcn_global_load_lds(
        (const __attribute__((address_space(1))) unsigned int*)g,
        (__attribute__((address_space(3))) unsigned int*)lds_base_uniform,
        16, 0, 0);
}

// ---------------- weight transpose + fp32->bf16 ----------------
// in: [R,C] fp32  ->  out: [C,R] bf16  (out rows contiguous in original R dim)
__global__ __launch_bounds__(256) void transpose_to_bf16(
    const float* __restrict__ in, unsigned short* __restrict__ out, int R, int C)
{
    __shared__ unsigned short tile[64][65];
    const int c0 = blockIdx.x * 64, r0 = blockIdx.y * 64;
    const int t = threadIdx.x;
    const int tc = t & 63, tr = t >> 6;
#pragma unroll
    for (int i = 0; i < 16; ++i) {
        int r = tr + i * 4;
        tile[r][tc] = f2bf(in[(long long)(r0 + r) * C + c0 + tc]);
    }
    __syncthreads();
    const int wr = t >> 3, wc = t & 7;
#pragma unroll
    for (int half = 0; half < 2; ++half) {
        int row = wr + half * 32;           // c_local -> output row
        u16x8 v;
#pragma unroll
        for (int j = 0; j < 8; ++j) v[j] = tile[wc * 8 + j][row];
        *(u16x8*)(out + (long long)(c0 + row) * R + r0 + wc * 8) = v;
    }
}

// ---------------- embedding bag: gather + sum-pool -> bf16 ----------------
__global__ __launch_bounds__(256) void embed_pool(
    const int* __restrict__ x, const float* __restrict__ emb,
    unsigned short* __restrict__ feat)
{
    int bag  = blockIdx.x * 4 + (threadIdx.x >> 6);   // [0, BATCH*FEATS)
    int lane = threadIdx.x & 63;
    int b = bag / FEATS;
    int f = bag - b * FEATS;
    const int* xs = x + (long long)bag * BAG;
    float s = 0.f;
#pragma unroll
    for (int l = 0; l < BAG; ++l) {
        int id = xs[l];
        s += emb[(long long)id * EDIM + lane];
    }
    feat[(long long)b * INDIM + f * EDIM + lane] = f2bf(s);
}

// ---------------- bf16 MFMA GEMM, 128x128 tile, BK=32, async LDS staging ----
// out = relu?(A @ W + bias [+ res]) ; A [M,K] bf16, Wt [N,K] bf16 (pre-transposed),
// bias fp32, res/out bf16.
__global__ __launch_bounds__(256) void gemm_bf16(
    const unsigned short* __restrict__ A, const unsigned short* __restrict__ Wt,
    const float* __restrict__ bias, const unsigned short* __restrict__ res,
    unsigned short* __restrict__ out, int M, int N, int K, int do_relu)
{
    __shared__ unsigned short As[128 * 32];   // [m][k], 8 KB
    __shared__ unsigned short Bs[128 * 32];   // [n][k], 8 KB

    const int t    = threadIdx.x;
    const int bCol = blockIdx.x * 128;
    const int bRow = blockIdx.y * 128;
    const int wave = t >> 6, lane = t & 63;
    const int wm = wave & 1, wn = wave >> 1;
    const int lm = lane & 15, quad = lane >> 4;

    // async staging map: chunk c = wave*2+it covers LDS rows [c*16, c*16+16).
    // lane l -> row c*16 + l/4, k = (l%4)*8 (8 bf16 = 16B).
    const int srow = (lane >> 2);
    const int sk   = (lane & 3) * 8;

    f32x4 acc[4][4] = {};

    for (int kt = 0; kt < K; kt += 32) {
#pragma unroll
        for (int it = 0; it < 2; ++it) {
            int c = wave * 2 + it;
            int row = c * 16 + srow;
            async_cp16(A  + (long long)(bRow + row) * K + kt + sk, As + c * 512);
            async_cp16(Wt + (long long)(bCol + row) * K + kt + sk, Bs + c * 512);
        }
        __syncthreads();

        bf16x8 a[4], b[4];
#pragma unroll
        for (int i = 0; i < 4; ++i)
            a[i] = *(const bf16x8*)&As[(wm * 64 + i * 16 + lm) * 32 + quad * 8];
#pragma unroll
        for (int j = 0; j < 4; ++j)
            b[j] = *(const bf16x8*)&Bs[(wn * 64 + j * 16 + lm) * 32 + quad * 8];
#pragma unroll
        for (int i = 0; i < 4; ++i)
#pragma unroll
            for (int j = 0; j < 4; ++j)
                acc[i][j] = __builtin_amdgcn_mfma_f32_16x16x32_bf16(
                    a[i], b[j], acc[i][j], 0, 0, 0);
        __syncthreads();
    }

    // ---- epilogue: bias (+res) (+relu), bf16 out ----
#pragma unroll
    for (int i = 0; i < 4; ++i) {
#pragma unroll
        for (int j = 0; j < 4; ++j) {
            int col = bCol + wn * 64 + j * 16 + lm;
            float bv = bias[col];
#pragma unroll
            for (int r = 0; r < 4; ++r) {
                int row = bRow + wm * 64 + i * 16 + quad * 4 + r;
                float v = acc[i][j][r] + bv;
                if (res) v += bf2f(res[(long long)row * N + col]);
                if (do_relu) v = fmaxf(v, 0.f);
                out[(long long)row * N + col] = f2bf(v);
            }
        }
    }
}

// ---------------- final linear + sigmoid ----------------
__global__ __launch_bounds__(256) void final_head(
    const unsigned short* __restrict__ feat, const float* __restrict__ lin_w,
    const float* __restrict__ lin_b, float* __restrict__ out)
{
    int row  = blockIdx.x * 4 + (threadIdx.x >> 6);
    int lane = threadIdx.x & 63;
    const unsigned short* fr = feat + (long long)row * INDIM;
    float s = 0.f;
#pragma unroll
    for (int it = 0; it < INDIM / 64; ++it)
        s += bf2f(fr[it * 64 + lane]) * lin_w[it * 64 + lane];
#pragma unroll
    for (int off = 32; off; off >>= 1)
        s += __shfl_down(s, off, 64);
    if (lane == 0)
        out[row] = 1.f / (1.f + __expf(-(s + lin_b[0])));
}

extern "C" void kernel_launch(void* const* d_in, const int* in_sizes, int n_in,
                              void* d_out, int out_size, void* d_ws, size_t ws_size,
                              hipStream_t stream) {
    const int*   x    = (const int*)  d_in[0];
    const float* emb  = (const float*)d_in[1];
    const float* w1_0 = (const float*)d_in[2];
    const float* b1_0 = (const float*)d_in[3];
    const float* w2_0 = (const float*)d_in[4];
    const float* b2_0 = (const float*)d_in[5];
    const float* w1_1 = (const float*)d_in[6];
    const float* b1_1 = (const float*)d_in[7];
    const float* w2_1 = (const float*)d_in[8];
    const float* b2_1 = (const float*)d_in[9];
    const float* w1_2 = (const float*)d_in[10];
    const float* b1_2 = (const float*)d_in[11];
    const float* w2_2 = (const float*)d_in[12];
    const float* b2_2 = (const float*)d_in[13];
    const float* linw = (const float*)d_in[14];
    const float* linb = (const float*)d_in[15];
    float* out = (float*)d_out;

    // ws layout (bf16 elements)
    unsigned short* feat = (unsigned short*)d_ws;            // [4096,1664]
    unsigned short* h    = feat + (long long)BATCH * INDIM;  // [4096,1024]
    unsigned short* p    = h + (long long)BATCH * 1024;
    unsigned short* w1_0t = p; p += 1024 * INDIM;            // [1024,1664]
    unsigned short* w2_0t = p; p += INDIM * 1024;            // [1664,1024]
    unsigned short* w1_1t = p; p += 1024 * INDIM;
    unsigned short* w2_1t = p; p += INDIM * 1024;
    unsigned short* w1_2t = p; p += 512 * INDIM;             // [512,1664]
    unsigned short* w2_2t = p; p += INDIM * 512;             // [1664,512]

    // 0) weight transpose+convert: in [R,C] -> out [C,R] bf16
    transpose_to_bf16<<<dim3(1024/64, INDIM/64), 256, 0, stream>>>(w1_0, w1_0t, INDIM, 1024);
    transpose_to_bf16<<<dim3(INDIM/64, 1024/64), 256, 0, stream>>>(w2_0, w2_0t, 1024, INDIM);
    transpose_to_bf16<<<dim3(1024/64, INDIM/64), 256, 0, stream>>>(w1_1, w1_1t, INDIM, 1024);
    transpose_to_bf16<<<dim3(INDIM/64, 1024/64), 256, 0, stream>>>(w2_1, w2_1t, 1024, INDIM);
    transpose_to_bf16<<<dim3(512/64,  INDIM/64), 256, 0, stream>>>(w1_2, w1_2t, INDIM, 512);
    transpose_to_bf16<<<dim3(INDIM/64, 512/64),  256, 0, stream>>>(w2_2, w2_2t, 512, INDIM);

    // 1) embedding bag -> bf16 feat
    embed_pool<<<BATCH * FEATS / 4, 256, 0, stream>>>(x, emb, feat);

    // 2) residual blocks
    gemm_bf16<<<dim3(1024/128, BATCH/128), 256, 0, stream>>>(
        feat, w1_0t, b1_0, nullptr, h, BATCH, 1024, INDIM, 1);
    gemm_bf16<<<dim3(INDIM/128, BATCH/128), 256, 0, stream>>>(
        h, w2_0t, b2_0, feat, feat, BATCH, INDIM, 1024, 1);
    gemm_bf16<<<dim3(1024/128, BATCH/128), 256, 0, stream>>>(
        feat, w1_1t, b1_1, nullptr, h, BATCH, 1024, INDIM, 1);
    gemm_bf16<<<dim3(INDIM/128, BATCH/128), 256, 0, stream>>>(
        h, w2_1t, b2_1, feat, feat, BATCH, INDIM, 1024, 1);
    gemm_bf16<<<dim3(512/128, BATCH/128), 256, 0, stream>>>(
        feat, w1_2t, b1_2, nullptr, h, BATCH, 512, INDIM, 1);
    gemm_bf16<<<dim3(INDIM/128, BATCH/128), 256, 0, stream>>>(
        h, w2_2t, b2_2, feat, feat, BATCH, INDIM, 512, 1);

    // 3) head
    final_head<<<BATCH / 4, 256, 0, stream>>>(feat, linw, linb, out);
}

// Round 3
// 565.402 us; speedup vs baseline: 1.3794x; 1.1443x over previous
//
#include <hip/hip_runtime.h>
#include <hip/hip_bf16.h>

// Problem constants
#define BATCH 4096
#define FEATS 26
#define BAG   8
#define EDIM  64
#define INDIM 1664   // 26*64

typedef short bf16x8 __attribute__((ext_vector_type(8)));
typedef float f32x4  __attribute__((ext_vector_type(4)));
typedef unsigned short u16x8 __attribute__((ext_vector_type(8)));

__device__ __forceinline__ unsigned short f2bf(float f) {
    unsigned u = __float_as_uint(f);
    unsigned r = (u + 0x7FFFu + ((u >> 16) & 1u)) >> 16;
    return (unsigned short)r;
}
__device__ __forceinline__ float bf2f(unsigned short h) {
    return __uint_as_float((unsigned)h << 16);
}
// async global->LDS, 16B per lane. HW dst = wave-uniform base + lane*16.
__device__ __forceinline__ void async_cp16(const void* g, void* lds_base_uniform) {
    __builtin_amdgcn_global_load_lds(
        (const __attribute__((address_space(1))) unsigned int*)g,
        (__attribute__((address_space(3))) unsigned int*)lds_base_uniform,
        16, 0, 0);
}
// s_waitcnt with only vmcnt constrained (lgkm=15, exp=7 i.e. no wait)
#define WAITCNT_VM(n) __builtin_amdgcn_s_waitcnt(0x0F70 | (n))

// ---------------- weight transpose + fp32->bf16 ----------------
// in: [R,C] fp32  ->  out: [C,R] bf16
__global__ __launch_bounds__(256) void transpose_to_bf16(
    const float* __restrict__ in, unsigned short* __restrict__ out, int R, int C)
{
    __shared__ unsigned short tile[64][65];
    const int c0 = blockIdx.x * 64, r0 = blockIdx.y * 64;
    const int t = threadIdx.x;
    const int tc = t & 63, tr = t >> 6;
#pragma unroll
    for (int i = 0; i < 16; ++i) {
        int r = tr + i * 4;
        tile[r][tc] = f2bf(in[(long long)(r0 + r) * C + c0 + tc]);
    }
    __syncthreads();
    const int wr = t >> 3, wc = t & 7;
#pragma unroll
    for (int half = 0; half < 2; ++half) {
        int row = wr + half * 32;
        u16x8 v;
#pragma unroll
        for (int j = 0; j < 8; ++j) v[j] = tile[wc * 8 + j][row];
        *(u16x8*)(out + (long long)(c0 + row) * R + r0 + wc * 8) = v;
    }
}

// ---------------- embedding bag: gather + sum-pool -> bf16 ----------------
__global__ __launch_bounds__(256) void embed_pool(
    const int* __restrict__ x, const float* __restrict__ emb,
    unsigned short* __restrict__ feat)
{
    int bag  = blockIdx.x * 4 + (threadIdx.x >> 6);
    int lane = threadIdx.x & 63;
    int b = bag / FEATS;
    int f = bag - b * FEATS;
    const int* xs = x + (long long)bag * BAG;
    float s = 0.f;
#pragma unroll
    for (int l = 0; l < BAG; ++l) {
        int id = xs[l];
        s += emb[(long long)id * EDIM + lane];
    }
    feat[(long long)b * INDIM + f * EDIM + lane] = f2bf(s);
}

// ------------- bf16 MFMA GEMM, 128x128 tile, BK=32, 4-deep async pipeline ----
// 512 threads = 8 waves; wave tile 64x32 (wm=wave&1 row-half, wn=wave>>1 col-quarter).
// LDS: 4 buffers x (A 8KB + B 8KB) = 64 KB. One s_barrier per K-iter, fine vmcnt.
// XOR swizzle: LDS slot (row, s) holds global k-chunk s ^ ((row>>1)&3)  (16B chunks).
#define NBUF 4
__global__ __launch_bounds__(512) void gemm_bf16(
    const unsigned short* __restrict__ A, const unsigned short* __restrict__ Wt,
    const float* __restrict__ bias, const unsigned short* __restrict__ res,
    unsigned short* __restrict__ out, int M, int N, int K, int do_relu)
{
    __shared__ unsigned short As[NBUF * 128 * 32];
    __shared__ unsigned short Bs[NBUF * 128 * 32];

    const int t    = threadIdx.x;
    const int bCol = blockIdx.x * 128;
    const int bRow = blockIdx.y * 128;
    const int wave = t >> 6, lane = t & 63;
    const int wm = wave & 1, wn = wave >> 1;       // wn in 0..3
    const int lm = lane & 15, quad = lane >> 4;

    // staging: wave w stages rows [w*16, w*16+16) of both tiles.
    // lane l -> row w*16 + l/4, loads global k-chunk ((l&3) ^ ((l>>3)&3)) (inverse swizzle)
    const int srow = lane >> 2;
    const int sq   = (lane & 3) ^ ((lane >> 3) & 3);
    const unsigned short* Ag = A  + (long long)(bRow + wave * 16 + srow) * K + sq * 8;
    const unsigned short* Bg = Wt + (long long)(bCol + wave * 16 + srow) * K + sq * 8;
    unsigned short* AsW = As + wave * 512;   // + buf*4096
    unsigned short* BsW = Bs + wave * 512;

    const int T = K / 32;
    f32x4 acc[4][2] = {};

    // fragment LDS read offsets (shorts): row*32 + slot*8, slot = quad ^ ((lm>>1)&3)
    const int slot = (quad ^ ((lm >> 1) & 3)) * 8;

#define ISSUE(tile_)  do { int _b = (tile_) & (NBUF - 1);                         \
        async_cp16(Ag + (long long)(tile_) * 32, AsW + _b * 4096);                \
        async_cp16(Bg + (long long)(tile_) * 32, BsW + _b * 4096); } while (0)

#define COMPUTE(tile_) do { int _b = (tile_) & (NBUF - 1);                        \
        const unsigned short* _a = As + _b * 4096;                                \
        const unsigned short* _bp = Bs + _b * 4096;                               \
        bf16x8 af[4], bf[2];                                                      \
        _Pragma("unroll")                                                         \
        for (int i = 0; i < 4; ++i)                                               \
            af[i] = *(const bf16x8*)&_a[(wm * 64 + i * 16 + lm) * 32 + slot];     \
        _Pragma("unroll")                                                         \
        for (int j = 0; j < 2; ++j)                                               \
            bf[j] = *(const bf16x8*)&_bp[(wn * 32 + j * 16 + lm) * 32 + slot];    \
        _Pragma("unroll")                                                         \
        for (int i = 0; i < 4; ++i)                                               \
            _Pragma("unroll")                                                     \
            for (int j = 0; j < 2; ++j)                                           \
                acc[i][j] = __builtin_amdgcn_mfma_f32_16x16x32_bf16(              \
                    af[i], bf[j], acc[i][j], 0, 0, 0); } while (0)

    ISSUE(0);
    ISSUE(1);
    for (int tt = 0; tt < T - 2; ++tt) {
        ISSUE(tt + 2);                 // lands in buf[(tt+2)&3] = buf[(tt-2)&3]: reads done
        WAITCNT_VM(4);                 // tile tt's 2 loads complete (t+1,t+2 still in flight)
        asm volatile("" ::: "memory");
        __builtin_amdgcn_s_barrier();
        asm volatile("" ::: "memory");
        COMPUTE(tt);
    }
    WAITCNT_VM(2);
    asm volatile("" ::: "memory");
    __builtin_amdgcn_s_barrier();
    asm volatile("" ::: "memory");
    COMPUTE(T - 2);
    WAITCNT_VM(0);
    asm volatile("" ::: "memory");
    __builtin_amdgcn_s_barrier();
    asm volatile("" ::: "memory");
    COMPUTE(T - 1);

    // ---- epilogue: bias (+res) (+relu), bf16 out ----
#pragma unroll
    for (int i = 0; i < 4; ++i) {
#pragma unroll
        for (int j = 0; j < 2; ++j) {
            int col = bCol + wn * 32 + j * 16 + lm;
            float bv = bias[col];
#pragma unroll
            for (int r = 0; r < 4; ++r) {
                int row = bRow + wm * 64 + i * 16 + quad * 4 + r;
                float v = acc[i][j][r] + bv;
                if (res) v += bf2f(res[(long long)row * N + col]);
                if (do_relu) v = fmaxf(v, 0.f);
                out[(long long)row * N + col] = f2bf(v);
            }
        }
    }
#undef ISSUE
#undef COMPUTE
}

// ---------------- final linear + sigmoid ----------------
__global__ __launch_bounds__(256) void final_head(
    const unsigned short* __restrict__ feat, const float* __restrict__ lin_w,
    const float* __restrict__ lin_b, float* __restrict__ out)
{
    int row  = blockIdx.x * 4 + (threadIdx.x >> 6);
    int lane = threadIdx.x & 63;
    const unsigned short* fr = feat + (long long)row * INDIM;
    float s = 0.f;
#pragma unroll
    for (int it = 0; it < INDIM / 64; ++it)
        s += bf2f(fr[it * 64 + lane]) * lin_w[it * 64 + lane];
#pragma unroll
    for (int off = 32; off; off >>= 1)
        s += __shfl_down(s, off, 64);
    if (lane == 0)
        out[row] = 1.f / (1.f + __expf(-(s + lin_b[0])));
}

extern "C" void kernel_launch(void* const* d_in, const int* in_sizes, int n_in,
                              void* d_out, int out_size, void* d_ws, size_t ws_size,
                              hipStream_t stream) {
    const int*   x    = (const int*)  d_in[0];
    const float* emb  = (const float*)d_in[1];
    const float* w1_0 = (const float*)d_in[2];
    const float* b1_0 = (const float*)d_in[3];
    const float* w2_0 = (const float*)d_in[4];
    const float* b2_0 = (const float*)d_in[5];
    const float* w1_1 = (const float*)d_in[6];
    const float* b1_1 = (const float*)d_in[7];
    const float* w2_1 = (const float*)d_in[8];
    const float* b2_1 = (const float*)d_in[9];
    const float* w1_2 = (const float*)d_in[10];
    const float* b1_2 = (const float*)d_in[11];
    const float* w2_2 = (const float*)d_in[12];
    const float* b2_2 = (const float*)d_in[13];
    const float* linw = (const float*)d_in[14];
    const float* linb = (const float*)d_in[15];
    float* out = (float*)d_out;

    // ws layout (bf16 elements)
    unsigned short* feat = (unsigned short*)d_ws;            // [4096,1664]
    unsigned short* h    = feat + (long long)BATCH * INDIM;  // [4096,1024]
    unsigned short* p    = h + (long long)BATCH * 1024;
    unsigned short* w1_0t = p; p += 1024 * INDIM;
    unsigned short* w2_0t = p; p += INDIM * 1024;
    unsigned short* w1_1t = p; p += 1024 * INDIM;
    unsigned short* w2_1t = p; p += INDIM * 1024;
    unsigned short* w1_2t = p; p += 512 * INDIM;
    unsigned short* w2_2t = p; p += INDIM * 512;

    // 0) weight transpose+convert: in [R,C] -> out [C,R] bf16
    transpose_to_bf16<<<dim3(1024/64, INDIM/64), 256, 0, stream>>>(w1_0, w1_0t, INDIM, 1024);
    transpose_to_bf16<<<dim3(INDIM/64, 1024/64), 256, 0, stream>>>(w2_0, w2_0t, 1024, INDIM);
    transpose_to_bf16<<<dim3(1024/64, INDIM/64), 256, 0, stream>>>(w1_1, w1_1t, INDIM, 1024);
    transpose_to_bf16<<<dim3(INDIM/64, 1024/64), 256, 0, stream>>>(w2_1, w2_1t, 1024, INDIM);
    transpose_to_bf16<<<dim3(512/64,  INDIM/64), 256, 0, stream>>>(w1_2, w1_2t, INDIM, 512);
    transpose_to_bf16<<<dim3(INDIM/64, 512/64),  256, 0, stream>>>(w2_2, w2_2t, 512, INDIM);

    // 1) embedding bag -> bf16 feat
    embed_pool<<<BATCH * FEATS / 4, 256, 0, stream>>>(x, emb, feat);

    // 2) residual blocks
    gemm_bf16<<<dim3(1024/128, BATCH/128), 512, 0, stream>>>(
        feat, w1_0t, b1_0, nullptr, h, BATCH, 1024, INDIM, 1);
    gemm_bf16<<<dim3(INDIM/128, BATCH/128), 512, 0, stream>>>(
        h, w2_0t, b2_0, feat, feat, BATCH, INDIM, 1024, 1);
    gemm_bf16<<<dim3(1024/128, BATCH/128), 512, 0, stream>>>(
        feat, w1_1t, b1_1, nullptr, h, BATCH, 1024, INDIM, 1);
    gemm_bf16<<<dim3(INDIM/128, BATCH/128), 512, 0, stream>>>(
        h, w2_1t, b2_1, feat, feat, BATCH, INDIM, 1024, 1);
    gemm_bf16<<<dim3(512/128, BATCH/128), 512, 0, stream>>>(
        feat, w1_2t, b1_2, nullptr, h, BATCH, 512, INDIM, 1);
    gemm_bf16<<<dim3(INDIM/128, BATCH/128), 512, 0, stream>>>(
        h, w2_2t, b2_2, feat, feat, BATCH, INDIM, 512, 1);

    // 3) head
    final_head<<<BATCH / 4, 256, 0, stream>>>(feat, linw, linb, out);
}